// Round 11
// baseline (38.711 us; speedup 1.0000x reference)
//
#include <hip/hip_runtime.h>
#include <stdint.h>

// Floyd-Steinberg halftoning, fused, 8-threads-per-tile (1 lane per column),
// with inline-asm buffer_load to FORCE all 24 loads in flight.
//
// R5/R8/R9/R10 showed hipcc's register allocator always re-chunks source-level
// load batches (R10: VGPR_Count=24 despite a single-source-batch of 24 loads),
// leaving ~6 serialized HBM latency exposures per thread. Here the 24 loads
// (3 ch x 8 rows, own column) are volatile inline-asm buffer_load_dword via an
// SRSRC descriptor (32-bit voffsets -> no 64-bit addr pairs; ~40 VGPRs total,
// under the 64-reg/8-wave cliff). Volatile asm cannot be reordered or split;
// outputs stay live until the single s_waitcnt vmcnt(0). sched_barrier(0)
// after the waitcnt stops hipcc hoisting consumers above it (guide rule #18).
//
// FS (transposed, matching reference swapaxes) runs redundantly in all 8
// lanes; column i's gray comes via __shfl(p[j], (lane&~7)|i) (compile-time p
// index). Each lane stores only its own column (3 planes). Every wave
// load/store instruction is a 256B-aligned dense 256B chunk.
// Exact reference math, contract(off): ((0.114*s0)+(0.587*s1))+(0.299*s2).

#define IMG_H 1024
#define IMG_W 1024
#define NCH   3

typedef uint32_t u32x4 __attribute__((ext_vector_type(4)));

__device__ __forceinline__ float bload(u32x4 rsrc, uint32_t voff_bytes) {
    float r;
    asm volatile("buffer_load_dword %0, %1, %2, 0 offen"
                 : "=v"(r) : "v"(voff_bytes), "s"(rsrc));
    return r;
}

__global__ __launch_bounds__(256, 6)
void fs_halftone_kernel(const float* __restrict__ in, float* __restrict__ out,
                        int n_imgs) {
#pragma clang fp contract(off)
    const int tiles_w = IMG_W / 8;                 // 128
    const int tiles_per_img = tiles_w * (IMG_H / 8);

    int gtid = blockIdx.x * blockDim.x + threadIdx.x;
    int tile = gtid >> 3;
    int col  = gtid & 7;                           // owned original column
    int lane = threadIdx.x & 63;
    int b  = tile / tiles_per_img;
    if (b >= n_imgs) return;
    int t  = tile % tiles_per_img;
    int th = t / tiles_w;
    int tw = t % tiles_w;

    const size_t imgstride = (size_t)IMG_H * IMG_W;
    const size_t col_off   = (size_t)(th * 8) * IMG_W + (size_t)(tw * 8) + (size_t)col;
    float* obase = out + (size_t)b * NCH * imgstride + col_off;

    // ---- SRSRC descriptor over the input buffer (bounds check disabled;
    //      all accesses in-bounds by construction) ----
    u32x4 rsrc;
    {
        uint64_t a = (uint64_t)(uintptr_t)in;
        rsrc.x = (uint32_t)a;
        rsrc.y = (uint32_t)(a >> 32);              // stride=0, no swizzle
        rsrc.z = 0xFFFFFFFFu;                      // num_records: disabled
        rsrc.w = 0x00020000u;                      // raw dword access
    }
    const uint32_t voff0 =
        (uint32_t)(((size_t)b * NCH * imgstride + col_off) * sizeof(float));

    // ---- 24 loads forced in flight (volatile asm), ONE wait ----
    float a0[8], a1[8], a2[8];
#pragma unroll
    for (int r = 0; r < 8; ++r)
        a0[r] = bload(rsrc, voff0 + (uint32_t)(0 * 4194304 + r * 4096));
#pragma unroll
    for (int r = 0; r < 8; ++r)
        a1[r] = bload(rsrc, voff0 + (uint32_t)(1 * 4194304 + r * 4096));
#pragma unroll
    for (int r = 0; r < 8; ++r)
        a2[r] = bload(rsrc, voff0 + (uint32_t)(2 * 4194304 + r * 4096));

    asm volatile("s_waitcnt vmcnt(0)" ::: "memory");
    __builtin_amdgcn_sched_barrier(0);             // rule #18: pin consumers after the wait

    // ---- gray (exact reference tree) + per-channel zero-masks, own column --
    float p[8];                                    // gray, index = row r
    unsigned int zm0 = 0u, zm1 = 0u, zm2 = 0u;     // bit r
#pragma unroll
    for (int r = 0; r < 8; ++r) {
        float s0 = a0[r] * 255.0f;
        float s1 = a1[r] * 255.0f;
        float s2 = a2[r] * 255.0f;
        if (s0 == 0.0f) zm0 |= 1u << r;
        if (s1 == 0.0f) zm1 |= 1u << r;
        if (s2 == 0.0f) zm2 |= 1u << r;
        p[r] = ((0.114f * s0) + (0.587f * s1)) + (0.299f * s2);
    }

    // ---- Floyd-Steinberg on the TRANSPOSED tile (redundant across 8 lanes).
    // FS row i == original column i; FS col j == original row j.
    float nrow[8];
#pragma unroll
    for (int j = 0; j < 8; ++j) nrow[j] = 0.0f;

    unsigned int ob = 0u;                          // own column on-bits, bit j

#pragma unroll
    for (int i = 0; i < 8; ++i) {
        // broadcast column i from its owner lane (compile-time p index)
        float cv[8];
#pragma unroll
        for (int j = 0; j < 8; ++j)
            cv[j] = __shfl(p[j], (lane & ~7) | i);

        float errs[8];
        float er = 0.0f;
        unsigned int onb = 0u;
#pragma unroll
        for (int j = 0; j < 8; ++j) {
            float px  = cv[j] + nrow[j];
            float old = px + er;
            bool  on  = old > 127.0f;
            float nw  = on ? 255.0f : 0.0f;
            float e   = old - nw;
            er = e * 0.4375f;                      // 7/16
            errs[j] = e;
            if (on) onb |= 1u << j;
        }
        if (col == i) ob = onb;                    // keep own column's bits
#pragma unroll
        for (int j = 0; j < 8; ++j) {
            float en = (j < 7) ? errs[j + 1] : 0.0f;
            float ep = (j > 0) ? errs[j - 1] : 0.0f;
            nrow[j] = ((0.3125f * errs[j]) + (0.1875f * en)) + (0.0625f * ep);
        }
    }

    // ---- stores: own column, all 3 planes; out = (scaled==0) ? 0 : ht/255 --
#pragma unroll
    for (int ch = 0; ch < 3; ++ch) {
        unsigned int zm = (ch == 0) ? zm0 : ((ch == 1) ? zm1 : zm2);
#pragma unroll
        for (int r = 0; r < 8; ++r) {
            bool on = (ob >> r) & 1u;
            bool z  = (zm >> r) & 1u;
            obase[ch * imgstride + (size_t)r * IMG_W] = (on && !z) ? 1.0f : 0.0f;
        }
    }
}

extern "C" void kernel_launch(void* const* d_in, const int* in_sizes, int n_in,
                              void* d_out, int out_size, void* d_ws, size_t ws_size,
                              hipStream_t stream) {
    const float* in  = (const float*)d_in[0];
    float*       out = (float*)d_out;

    int n_imgs = in_sizes[0] / (NCH * IMG_H * IMG_W);  // 8
    int total_threads = 8 * n_imgs * (IMG_H / 8) * (IMG_W / 8);  // 8 per tile
    int block = 256;
    int grid = (total_threads + block - 1) / block;
    fs_halftone_kernel<<<grid, block, 0, stream>>>(in, out, n_imgs);
}

// Round 12
// 38.240 us; speedup vs baseline: 1.0123x; 1.0123x over previous
//
#include <hip/hip_runtime.h>
#include <stdint.h>

// Floyd-Steinberg halftoning, fused, 8-lanes-per-tile, 2 tiles/thread with a
// counted-vmcnt software pipeline.
//
// R2-R11 post-mortem: every 1-cycle-per-thread variant plateaus at ~38us
// (~5.1 TB/s fabric) regardless of occupancy (17-60%) or VALU (13-42%) --
// bulk-synchronous phase-lock: all waves load, then all compute, then all
// store; phases never overlap. Fix: each thread owns tiles (tid, tid+half).
// All 48 loads issue back-to-back as VOLATILE inline-asm buffer_load_dword
// (allocator cannot re-chunk or sink them -- the R5/R9/R10 failure mode);
// s_waitcnt vmcnt(24) releases tile A while B's 24 loads remain in flight
// under A's gray+FS (~1000cy VALU); vmcnt(0) before store A => stores of A
// overlap gray+FS of B, and we never wait on stores. Rule #18: every waitcnt
// is followed by sched_barrier(0) so consumers can't hoist above it.
//
// FS runs on the TRANSPOSED tile (reference swapaxes), redundantly across the
// 8 lanes; column i of the tile is broadcast from its owner lane via
// __shfl(p[j], (lane&~7)|i) (compile-time p index). Exact reference math,
// contract(off): ((0.114*s0)+(0.587*s1))+(0.299*s2).
//
// Grid: 131072 tile-pairs... 65536 pairs x 8 lanes = 524288 threads = 2048
// blocks = 8 blocks/CU (all resident). __launch_bounds__(256,5): ~102-VGPR
// cap for the ~85-reg live set (A24 + B24 + p8 + FS state) -- spill margin.

#define IMG_H 1024
#define IMG_W 1024
#define NCH   3

typedef uint32_t u32x4 __attribute__((ext_vector_type(4)));

__device__ __forceinline__ float bload(u32x4 rsrc, uint32_t voff_bytes) {
    float r;
    asm volatile("buffer_load_dword %0, %1, %2, 0 offen"
                 : "=v"(r) : "v"(voff_bytes), "s"(rsrc));
    return r;
}

// gray + masks for one tile-column (exact reference tree)
__device__ __forceinline__ void gray_col(const float (&a0)[8], const float (&a1)[8],
                                         const float (&a2)[8], float (&p)[8],
                                         unsigned int& zm0, unsigned int& zm1,
                                         unsigned int& zm2) {
#pragma clang fp contract(off)
    zm0 = zm1 = zm2 = 0u;
#pragma unroll
    for (int r = 0; r < 8; ++r) {
        float s0 = a0[r] * 255.0f;
        float s1 = a1[r] * 255.0f;
        float s2 = a2[r] * 255.0f;
        if (s0 == 0.0f) zm0 |= 1u << r;
        if (s1 == 0.0f) zm1 |= 1u << r;
        if (s2 == 0.0f) zm2 |= 1u << r;
        p[r] = ((0.114f * s0) + (0.587f * s1)) + (0.299f * s2);
    }
}

// FS on the transposed tile; returns own column's on-bits (bit j = orig row j)
__device__ __forceinline__ unsigned int run_fs(const float (&p)[8], int lane, int col) {
#pragma clang fp contract(off)
    float nrow[8];
#pragma unroll
    for (int j = 0; j < 8; ++j) nrow[j] = 0.0f;
    unsigned int ob = 0u;
#pragma unroll
    for (int i = 0; i < 8; ++i) {
        float cv[8];
#pragma unroll
        for (int j = 0; j < 8; ++j)
            cv[j] = __shfl(p[j], (lane & ~7) | i);
        float errs[8];
        float er = 0.0f;
        unsigned int onb = 0u;
#pragma unroll
        for (int j = 0; j < 8; ++j) {
            float px  = cv[j] + nrow[j];
            float old = px + er;
            bool  on  = old > 127.0f;
            float nw  = on ? 255.0f : 0.0f;
            float e   = old - nw;
            er = e * 0.4375f;                      // 7/16
            errs[j] = e;
            if (on) onb |= 1u << j;
        }
        if (col == i) ob = onb;
#pragma unroll
        for (int j = 0; j < 8; ++j) {
            float en = (j < 7) ? errs[j + 1] : 0.0f;
            float ep = (j > 0) ? errs[j - 1] : 0.0f;
            nrow[j] = ((0.3125f * errs[j]) + (0.1875f * en)) + (0.0625f * ep);
        }
    }
    return ob;
}

__device__ __forceinline__ void store_col(float* obase, unsigned int ob,
                                          unsigned int zm0, unsigned int zm1,
                                          unsigned int zm2) {
    const size_t imgstride = (size_t)IMG_H * IMG_W;
#pragma unroll
    for (int ch = 0; ch < 3; ++ch) {
        unsigned int zm = (ch == 0) ? zm0 : ((ch == 1) ? zm1 : zm2);
#pragma unroll
        for (int r = 0; r < 8; ++r) {
            bool on = (ob >> r) & 1u;
            bool z  = (zm >> r) & 1u;
            obase[ch * imgstride + (size_t)r * IMG_W] = (on && !z) ? 1.0f : 0.0f;
        }
    }
}

__global__ __launch_bounds__(256, 5)
void fs_halftone_kernel(const float* __restrict__ in, float* __restrict__ out,
                        int n_imgs) {
#pragma clang fp contract(off)
    const int tiles_w = IMG_W / 8;                 // 128
    const int tiles_per_img = tiles_w * (IMG_H / 8);
    const int total_tiles = n_imgs * tiles_per_img;
    const int half = total_tiles >> 1;             // tiles per pipeline stage

    int gtid = blockIdx.x * blockDim.x + threadIdx.x;
    int pairid = gtid >> 3;                        // [0, half)
    int col  = gtid & 7;                           // owned original column
    int lane = threadIdx.x & 63;
    if (pairid >= half) return;

    const size_t imgstride = (size_t)IMG_H * IMG_W;

    // element offsets of the two tiles' owned columns
    auto tile_elem_off = [&](int T) -> size_t {
        int b  = T / tiles_per_img;
        int t  = T % tiles_per_img;
        int th = t / tiles_w;
        int tw = t % tiles_w;
        return (size_t)b * NCH * imgstride + (size_t)(th * 8) * IMG_W
             + (size_t)(tw * 8) + (size_t)col;
    };
    const size_t offA = tile_elem_off(pairid);
    const size_t offB = tile_elem_off(pairid + half);

    // SRSRC over the input (bounds check disabled; in-bounds by construction)
    u32x4 rsrc;
    {
        uint64_t a = (uint64_t)(uintptr_t)in;
        rsrc.x = (uint32_t)a;
        rsrc.y = (uint32_t)(a >> 32);
        rsrc.z = 0xFFFFFFFFu;
        rsrc.w = 0x00020000u;
    }
    const uint32_t vA = (uint32_t)(offA * sizeof(float));
    const uint32_t vB = (uint32_t)(offB * sizeof(float));

    // ---- issue ALL 48 loads back-to-back (A then B), volatile asm ----
    float a0[8], a1[8], a2[8], b0[8], b1[8], b2[8];
#pragma unroll
    for (int r = 0; r < 8; ++r) a0[r] = bload(rsrc, vA + (uint32_t)(0 * 4194304 + r * 4096));
#pragma unroll
    for (int r = 0; r < 8; ++r) a1[r] = bload(rsrc, vA + (uint32_t)(1 * 4194304 + r * 4096));
#pragma unroll
    for (int r = 0; r < 8; ++r) a2[r] = bload(rsrc, vA + (uint32_t)(2 * 4194304 + r * 4096));
#pragma unroll
    for (int r = 0; r < 8; ++r) b0[r] = bload(rsrc, vB + (uint32_t)(0 * 4194304 + r * 4096));
#pragma unroll
    for (int r = 0; r < 8; ++r) b1[r] = bload(rsrc, vB + (uint32_t)(1 * 4194304 + r * 4096));
#pragma unroll
    for (int r = 0; r < 8; ++r) b2[r] = bload(rsrc, vB + (uint32_t)(2 * 4194304 + r * 4096));

    // ---- wait for A only (24 B-loads stay in flight) ----
    asm volatile("s_waitcnt vmcnt(24)" ::: "memory");
    __builtin_amdgcn_sched_barrier(0);

    float pA[8];
    unsigned int zA0, zA1, zA2;
    gray_col(a0, a1, a2, pA, zA0, zA1, zA2);
    unsigned int obA = run_fs(pA, lane, col);      // ~1000cy VALU hides B latency

    // ---- B has arrived; then store A so stores overlap B's compute ----
    asm volatile("s_waitcnt vmcnt(0)" ::: "memory");
    __builtin_amdgcn_sched_barrier(0);

    store_col(out + offA, obA, zA0, zA1, zA2);

    float pB[8];
    unsigned int zB0, zB1, zB2;
    gray_col(b0, b1, b2, pB, zB0, zB1, zB2);
    unsigned int obB = run_fs(pB, lane, col);
    store_col(out + offB, obB, zB0, zB1, zB2);
}

extern "C" void kernel_launch(void* const* d_in, const int* in_sizes, int n_in,
                              void* d_out, int out_size, void* d_ws, size_t ws_size,
                              hipStream_t stream) {
    const float* in  = (const float*)d_in[0];
    float*       out = (float*)d_out;

    int n_imgs = in_sizes[0] / (NCH * IMG_H * IMG_W);  // 8
    int total_tiles = n_imgs * (IMG_H / 8) * (IMG_W / 8);
    int half = total_tiles / 2;
    int total_threads = 8 * half;                  // 8 lanes x tile-pairs
    int block = 256;
    int grid = (total_threads + block - 1) / block;
    fs_halftone_kernel<<<grid, block, 0, stream>>>(in, out, n_imgs);
}